// Round 1
// baseline (248.659 us; speedup 1.0000x reference)
//
#include <hip/hip_runtime.h>
#include <stdint.h>
#include <math.h>

typedef __attribute__((ext_vector_type(4))) float  f4;
typedef __attribute__((ext_vector_type(4))) float  f32x4;
typedef __attribute__((ext_vector_type(8))) short  bf16x8;
typedef __attribute__((ext_vector_type(4))) short  s16x4;

#define NB   16
#define LSEQ 4096
#define DH   64
#define QB   128
#define KVB  64
#define NW   4

__device__ __forceinline__ short f2bf(float f) {
    union { float f; uint32_t u; } v; v.f = f;
    return (short)((v.u + 0x7FFFu + ((v.u >> 16) & 1u)) >> 16);
}

__global__ __launch_bounds__(256, 2) void fa_fwd(
    const float* __restrict__ Q, const float* __restrict__ K,
    const float* __restrict__ V, float* __restrict__ O)
{
    // K tile: row-major [kv][d] bf16 with XOR swizzle ((kv&7)<<3 on short index)
    __shared__ __align__(16) short k_lds[KVB * DH];
    // V tile: kv-oct subtiled [g=kv>>3][d][kv&7]
    __shared__ __align__(16) short v_lds[KVB * DH];
    // P buffer per wave: [32 q][64 kv] with row stride 72 (16B-aligned, pad kills conflicts)
    __shared__ __align__(16) short p_lds[NW][32 * 72];

    const int tid  = threadIdx.x;
    const int lane = tid & 63;
    const int w    = tid >> 6;
    const int lo   = lane & 15;
    const int hi   = lane >> 4;

    const int b  = blockIdx.x >> 5;
    const int qt = blockIdx.x & 31;
    const int q0 = qt * QB + w * 32;

    const float* Qb = Q + (size_t)b * LSEQ * DH;
    const float* Kb = K + (size_t)b * LSEQ * DH;
    const float* Vb = V + (size_t)b * LSEQ * DH;
    float*       Ob = O + (size_t)b * LSEQ * DH;

    // ---- Q fragments, 1/8 scale folded into the bf16 cast ----
    bf16x8 qf[2][2];
#pragma unroll
    for (int r = 0; r < 2; ++r)
#pragma unroll
      for (int kb = 0; kb < 2; ++kb) {
        const int row = q0 + r * 16 + lo;
        const int d0  = 32 * kb + 8 * hi;
        f4 a = *(const f4*)&Qb[row * DH + d0];
        f4 c = *(const f4*)&Qb[row * DH + d0 + 4];
        bf16x8 f;
        f[0] = f2bf(a[0] * 0.125f); f[1] = f2bf(a[1] * 0.125f);
        f[2] = f2bf(a[2] * 0.125f); f[3] = f2bf(a[3] * 0.125f);
        f[4] = f2bf(c[0] * 0.125f); f[5] = f2bf(c[1] * 0.125f);
        f[6] = f2bf(c[2] * 0.125f); f[7] = f2bf(c[3] * 0.125f);
        qf[r][kb] = f;
      }

    f32x4 o_acc[2][4];
#pragma unroll
    for (int r = 0; r < 2; ++r)
#pragma unroll
      for (int cd = 0; cd < 4; ++cd)
        o_acc[r][cd] = (f32x4){0.f, 0.f, 0.f, 0.f};

    float m_run[2][4], l_run[2][4];
#pragma unroll
    for (int r = 0; r < 2; ++r)
#pragma unroll
      for (int g = 0; g < 4; ++g) { m_run[r][g] = -INFINITY; l_run[r][g] = 0.f; }

    for (int it = 0; it < LSEQ / KVB; ++it) {
        const int kv0 = it * KVB;

        // ---- stage K (coalesced f4 rows -> swizzled row-major LDS) ----
#pragma unroll
        for (int i = 0; i < 4; ++i) {
            const int kv = (tid >> 4) + 16 * i;
            const int d0 = (tid & 15) * 4;
            f4 x = *(const f4*)&Kb[(size_t)(kv0 + kv) * DH + d0];
            s16x4 p;
            p[0] = f2bf(x[0]); p[1] = f2bf(x[1]);
            p[2] = f2bf(x[2]); p[3] = f2bf(x[3]);
            *(s16x4*)&k_lds[kv * DH + (d0 ^ ((kv & 7) << 3))] = p;
        }
        // ---- stage V (per-thread kv-run of 8 for one d; conflict-free b128 writes) ----
        {
            const int d  = tid & 63;
            const int wg = tid >> 6;
#pragma unroll
            for (int hB = 0; hB < 2; ++hB) {
                const int g = wg + 4 * hB;
                bf16x8 p;
#pragma unroll
                for (int j = 0; j < 8; ++j)
                    p[j] = f2bf(Vb[(size_t)(kv0 + g * 8 + j) * DH + d]);
                *(bf16x8*)&v_lds[g * 512 + d * 8] = p;
            }
        }
        __syncthreads();

        // ---- S = (Q/8) K^T : lane holds S[q = 4*hi + reg (+16r)][kv = c*16 + lo] ----
        f32x4 s[2][4];
#pragma unroll
        for (int r = 0; r < 2; ++r)
#pragma unroll
          for (int c = 0; c < 4; ++c)
            s[r][c] = (f32x4){0.f, 0.f, 0.f, 0.f};

#pragma unroll
        for (int c = 0; c < 4; ++c) {
            const int row = c * 16 + lo;
#pragma unroll
            for (int kb = 0; kb < 2; ++kb) {
                const int d0 = 32 * kb + 8 * hi;
                bf16x8 kf = *(const bf16x8*)&k_lds[row * DH + (d0 ^ ((row & 7) << 3))];
                s[0][c] = __builtin_amdgcn_mfma_f32_16x16x32_bf16(qf[0][kb], kf, s[0][c], 0, 0, 0);
                s[1][c] = __builtin_amdgcn_mfma_f32_16x16x32_bf16(qf[1][kb], kf, s[1][c], 0, 0, 0);
            }
        }

        // ---- online softmax (row = reduce over lo lanes) ----
#pragma unroll
        for (int r = 0; r < 2; ++r)
#pragma unroll
          for (int g = 0; g < 4; ++g) {
            float mx = fmaxf(fmaxf(s[r][0][g], s[r][1][g]), fmaxf(s[r][2][g], s[r][3][g]));
            mx = fmaxf(mx, __shfl_xor(mx, 1));
            mx = fmaxf(mx, __shfl_xor(mx, 2));
            mx = fmaxf(mx, __shfl_xor(mx, 4));
            mx = fmaxf(mx, __shfl_xor(mx, 8));
            const float mn = fmaxf(m_run[r][g], mx);
            const float cr = __expf(m_run[r][g] - mn);
            m_run[r][g] = mn;
            float rs = 0.f;
#pragma unroll
            for (int c = 0; c < 4; ++c) {
                const float p = __expf(s[r][c][g] - mn);
                rs += p;
                p_lds[w][(r * 16 + 4 * hi + g) * 72 + c * 16 + lo] = f2bf(p);
            }
            rs += __shfl_xor(rs, 1);
            rs += __shfl_xor(rs, 2);
            rs += __shfl_xor(rs, 4);
            rs += __shfl_xor(rs, 8);
            l_run[r][g] = l_run[r][g] * cr + rs;
#pragma unroll
            for (int cd = 0; cd < 4; ++cd) o_acc[r][cd][g] *= cr;
          }

        // ---- O += P V ----
#pragma unroll
        for (int ks = 0; ks < 2; ++ks) {
            bf16x8 pf0 = *(const bf16x8*)&p_lds[w][(0 * 16 + lo) * 72 + 8 * hi + 32 * ks];
            bf16x8 pf1 = *(const bf16x8*)&p_lds[w][(1 * 16 + lo) * 72 + 8 * hi + 32 * ks];
#pragma unroll
            for (int cd = 0; cd < 4; ++cd) {
                bf16x8 vf = *(const bf16x8*)&v_lds[(hi + 4 * ks) * 512 + (cd * 16 + lo) * 8];
                o_acc[0][cd] = __builtin_amdgcn_mfma_f32_16x16x32_bf16(pf0, vf, o_acc[0][cd], 0, 0, 0);
                o_acc[1][cd] = __builtin_amdgcn_mfma_f32_16x16x32_bf16(pf1, vf, o_acc[1][cd], 0, 0, 0);
            }
        }
        __syncthreads();
    }

    // ---- epilogue: normalize by row sum, store fp32 ----
#pragma unroll
    for (int r = 0; r < 2; ++r)
#pragma unroll
      for (int g = 0; g < 4; ++g) {
        const float inv = 1.0f / l_run[r][g];
        const int row = q0 + r * 16 + 4 * hi + g;
#pragma unroll
        for (int cd = 0; cd < 4; ++cd)
            Ob[(size_t)row * DH + cd * 16 + lo] = o_acc[r][cd][g] * inv;
      }
}

extern "C" void kernel_launch(void* const* d_in, const int* in_sizes, int n_in,
                              void* d_out, int out_size, void* d_ws, size_t ws_size,
                              hipStream_t stream) {
    (void)in_sizes; (void)n_in; (void)d_ws; (void)ws_size; (void)out_size;
    const float* q = (const float*)d_in[0];
    const float* k = (const float*)d_in[1];
    const float* v = (const float*)d_in[2];
    float* o = (float*)d_out;
    dim3 grid(NB * (LSEQ / QB));
    dim3 block(256);
    hipLaunchKernelGGL(fa_fwd, grid, block, 0, stream, q, k, v, o);
}

// Round 2
// 157.624 us; speedup vs baseline: 1.5775x; 1.5775x over previous
//
#include <hip/hip_runtime.h>
#include <stdint.h>
#include <math.h>

typedef __attribute__((ext_vector_type(4)))  float f4;
typedef __attribute__((ext_vector_type(16))) float f32x16;
typedef __attribute__((ext_vector_type(8)))  short bf16x8;

#define NB   16
#define LSEQ 4096
#define DH   64
#define QB   128   // 4 waves x 32 q-rows
#define KVB  64

__device__ __forceinline__ short f2bf(float f) {
    union { float f; uint32_t u; } v; v.f = f;
    return (short)((v.u + 0x7FFFu + ((v.u >> 16) & 1u)) >> 16);
}

__device__ __forceinline__ uint32_t cvtpk(float lo, float hi) {
    uint32_t r;
    asm("v_cvt_pk_bf16_f32 %0, %1, %2" : "=v"(r) : "v"(lo), "v"(hi));
    return r;
}

__global__ __launch_bounds__(256, 2) void fa_fwd(
    const float* __restrict__ Q, const float* __restrict__ K,
    const float* __restrict__ V, float* __restrict__ O)
{
    // K tile: [kv][d] bf16, granule-XOR swizzle (d_short ^ ((kv&7)<<3))
    __shared__ __align__(16) short k_lds[KVB * DH];
    // V^T tile: [d][kv] bf16, granule-XOR swizzle (kv granule ^ (d&7))
    __shared__ __align__(16) short v_lds[DH * KVB];

    const int tid  = threadIdx.x;
    const int lane = tid & 63;
    const int w    = tid >> 6;
    const int l31  = lane & 31;
    const int H    = lane >> 5;

    const int b  = blockIdx.x >> 5;
    const int qt = blockIdx.x & 31;
    const int q0 = qt * QB + w * 32;

    const float* Qb = Q + (size_t)b * LSEQ * DH;
    const float* Kb = K + (size_t)b * LSEQ * DH;
    const float* Vb = V + (size_t)b * LSEQ * DH;
    float*       Ob = O + (size_t)b * LSEQ * DH;

    // scores/8 in log2 domain: fold 0.125*log2(e) into Q cast
    const float QS = 0.125f * 1.44269504088896340736f;

    // ---- Q fragments (B-operand: col=q=lane&31, k = 8H+j within 16-chunk kb) ----
    bf16x8 qf[4];
#pragma unroll
    for (int kb = 0; kb < 4; ++kb) {
        const float* src = Qb + (size_t)(q0 + l31) * DH + 16 * kb + 8 * H;
        f4 a = *(const f4*)src;
        f4 c = *(const f4*)(src + 4);
        bf16x8 f;
        f[0] = f2bf(a[0] * QS); f[1] = f2bf(a[1] * QS);
        f[2] = f2bf(a[2] * QS); f[3] = f2bf(a[3] * QS);
        f[4] = f2bf(c[0] * QS); f[5] = f2bf(c[1] * QS);
        f[6] = f2bf(c[2] * QS); f[7] = f2bf(c[3] * QS);
        qf[kb] = f;
    }

    // O^T accumulators: oacc[dt] holds O^T[d=32dt+(r&3)+8(r>>2)+4H][q=lane&31]
    f32x16 oacc0, oacc1;
#pragma unroll
    for (int i = 0; i < 16; ++i) { oacc0[i] = 0.f; oacc1[i] = 0.f; }

    float m_run = -INFINITY;
    float l_run = 0.f;

    for (int it = 0; it < LSEQ / KVB; ++it) {
        const int kv0 = it * KVB;

        // ---- stage K: thread covers [kv][8d], coalesced 32B reads ----
#pragma unroll
        for (int p = 0; p < 2; ++p) {
            const int kv = (tid >> 3) + 32 * p;
            const int d0 = (tid & 7) * 8;
            const float* src = Kb + (size_t)(kv0 + kv) * DH + d0;
            f4 a = *(const f4*)src;
            f4 c = *(const f4*)(src + 4);
            bf16x8 f;
            f[0] = f2bf(a[0]); f[1] = f2bf(a[1]); f[2] = f2bf(a[2]); f[3] = f2bf(a[3]);
            f[4] = f2bf(c[0]); f[5] = f2bf(c[1]); f[6] = f2bf(c[2]); f[7] = f2bf(c[3]);
            *(bf16x8*)&k_lds[kv * DH + (d0 ^ ((kv & 7) << 3))] = f;
        }
        // ---- stage V^T: thread gathers a kv-run of 8 for one d (coalesced per j) ----
        {
            const int d  = tid & 63;
            const int wg = tid >> 6;
#pragma unroll
            for (int hB = 0; hB < 2; ++hB) {
                const int g = wg + 4 * hB;
                bf16x8 f;
#pragma unroll
                for (int j = 0; j < 8; ++j)
                    f[j] = f2bf(Vb[(size_t)(kv0 + 8 * g + j) * DH + d]);
                *(bf16x8*)&v_lds[d * KVB + 8 * (g ^ (d & 7))] = f;
            }
        }
        __syncthreads();

        // ---- S^T = K Q^T (swapped): lane holds S^T[kv=32c+(r&3)+8(r>>2)+4H][q=lane&31]
        f32x16 s0, s1;
#pragma unroll
        for (int i = 0; i < 16; ++i) { s0[i] = 0.f; s1[i] = 0.f; }
#pragma unroll
        for (int kb = 0; kb < 4; ++kb) {
            const int d0 = 16 * kb + 8 * H;
            bf16x8 kf0 = *(const bf16x8*)&k_lds[(l31)      * DH + (d0 ^ ((l31 & 7) << 3))];
            bf16x8 kf1 = *(const bf16x8*)&k_lds[(32 + l31) * DH + (d0 ^ ((l31 & 7) << 3))];
            s0 = __builtin_amdgcn_mfma_f32_32x32x16_bf16(kf0, qf[kb], s0, 0, 0, 0);
            s1 = __builtin_amdgcn_mfma_f32_32x32x16_bf16(kf1, qf[kb], s1, 0, 0, 0);
        }

        // ---- online softmax, fully per-lane (one q per lane) ----
        float mx = s0[0];
#pragma unroll
        for (int i = 1; i < 16; ++i) mx = fmaxf(mx, s0[i]);
#pragma unroll
        for (int i = 0; i < 16; ++i) mx = fmaxf(mx, s1[i]);
        mx = fmaxf(mx, __shfl_xor(mx, 32));

        const float mn   = fmaxf(m_run, mx);
        const float corr = __builtin_amdgcn_exp2f(m_run - mn);
        m_run = mn;

        float rs = 0.f;
#pragma unroll
        for (int i = 0; i < 16; ++i) { s0[i] = __builtin_amdgcn_exp2f(s0[i] - mn); rs += s0[i]; }
#pragma unroll
        for (int i = 0; i < 16; ++i) { s1[i] = __builtin_amdgcn_exp2f(s1[i] - mn); rs += s1[i]; }
        rs += __shfl_xor(rs, 32);
        l_run = l_run * corr + rs;

#pragma unroll
        for (int i = 0; i < 16; ++i) { oacc0[i] *= corr; oacc1[i] *= corr; }

        // ---- P^T (f32 regs) -> PV B-fragments via cvt_pk + permlane32_swap ----
        bf16x8 pa[4];
#define MAKE_PA(P, ks2, dst)                                                    \
        {                                                                       \
            uint32_t a1 = cvtpk(P[8*(ks2)+0], P[8*(ks2)+1]);                    \
            uint32_t b1 = cvtpk(P[8*(ks2)+4], P[8*(ks2)+5]);                    \
            uint32_t a2 = cvtpk(P[8*(ks2)+2], P[8*(ks2)+3]);                    \
            uint32_t b2 = cvtpk(P[8*(ks2)+6], P[8*(ks2)+7]);                    \
            asm volatile("v_permlane32_swap_b32 %0, %1" : "+v"(a1), "+v"(b1));  \
            asm volatile("v_permlane32_swap_b32 %0, %1" : "+v"(a2), "+v"(b2));  \
            union { bf16x8 v; uint32_t u[4]; } t;                               \
            t.u[0] = a1; t.u[1] = a2; t.u[2] = b1; t.u[3] = b2;                 \
            dst = t.v;                                                          \
        }
        MAKE_PA(s0, 0, pa[0]);
        MAKE_PA(s0, 1, pa[1]);
        MAKE_PA(s1, 0, pa[2]);
        MAKE_PA(s1, 1, pa[3]);
#undef MAKE_PA

        // ---- O^T += V^T P^T ----
#pragma unroll
        for (int ks = 0; ks < 4; ++ks) {
            const int d0g = 2 * ks + H;
            bf16x8 vf0 = *(const bf16x8*)&v_lds[(l31)      * KVB + 8 * (d0g ^ (l31 & 7))];
            bf16x8 vf1 = *(const bf16x8*)&v_lds[(32 + l31) * KVB + 8 * (d0g ^ (l31 & 7))];
            oacc0 = __builtin_amdgcn_mfma_f32_32x32x16_bf16(vf0, pa[ks], oacc0, 0, 0, 0);
            oacc1 = __builtin_amdgcn_mfma_f32_32x32x16_bf16(vf1, pa[ks], oacc1, 0, 0, 0);
        }
        __syncthreads();
    }

    // ---- epilogue: O[q][d] = O^T/l, f4 stores (reg&3 spans 4 consecutive d) ----
    const float inv = 1.0f / l_run;
    const int q = q0 + l31;
#pragma unroll
    for (int k = 0; k < 4; ++k) {
        f4 o0, o1;
#pragma unroll
        for (int m = 0; m < 4; ++m) { o0[m] = oacc0[4*k+m] * inv; o1[m] = oacc1[4*k+m] * inv; }
        *(f4*)&Ob[(size_t)q * DH +      8 * k + 4 * H] = o0;
        *(f4*)&Ob[(size_t)q * DH + 32 + 8 * k + 4 * H] = o1;
    }
}

extern "C" void kernel_launch(void* const* d_in, const int* in_sizes, int n_in,
                              void* d_out, int out_size, void* d_ws, size_t ws_size,
                              hipStream_t stream) {
    (void)in_sizes; (void)n_in; (void)d_ws; (void)ws_size; (void)out_size;
    const float* q = (const float*)d_in[0];
    const float* k = (const float*)d_in[1];
    const float* v = (const float*)d_in[2];
    float* o = (float*)d_out;
    dim3 grid(NB * (LSEQ / QB));
    dim3 block(256);
    hipLaunchKernelGGL(fa_fwd, grid, block, 0, stream, q, k, v, o);
}

// Round 3
// 115.352 us; speedup vs baseline: 2.1557x; 1.3665x over previous
//
#include <hip/hip_runtime.h>
#include <stdint.h>
#include <math.h>

typedef __attribute__((ext_vector_type(4)))  float f4;
typedef __attribute__((ext_vector_type(16))) float f32x16;
typedef __attribute__((ext_vector_type(8)))  short bf16x8;

#define NB   16
#define LSEQ 4096
#define DH   64
#define QB   128   // 4 waves x 32 q-rows
#define KVB  64
#define NT   (LSEQ / KVB)

__device__ __forceinline__ short f2bf(float f) {
    union { float f; uint32_t u; } v; v.f = f;
    return (short)((v.u + 0x7FFFu + ((v.u >> 16) & 1u)) >> 16);
}

__device__ __forceinline__ uint32_t cvtpk(float lo, float hi) {
    uint32_t r;
    asm("v_cvt_pk_bf16_f32 %0, %1, %2" : "=v"(r) : "v"(lo), "v"(hi));
    return r;
}

__global__ __launch_bounds__(256, 2) void fa_fwd(
    const float* __restrict__ Q, const float* __restrict__ K,
    const float* __restrict__ V, float* __restrict__ O)
{
    // double-buffered tiles
    // K: [kv][d] bf16, granule-XOR swizzle (d_short ^ ((kv&7)<<3))
    __shared__ __align__(16) short k_lds[2][KVB * DH];
    // V^T: [d][kv] bf16, granule-XOR swizzle (kv granule ^ (d&7))
    __shared__ __align__(16) short v_lds[2][DH * KVB];

    const int tid  = threadIdx.x;
    const int lane = tid & 63;
    const int w    = tid >> 6;
    const int l31  = lane & 31;
    const int H    = lane >> 5;

    const int b  = blockIdx.x >> 5;
    const int qt = blockIdx.x & 31;
    const int q0 = qt * QB + w * 32;

    const float* Qb = Q + (size_t)b * LSEQ * DH;
    const float* Kb = K + (size_t)b * LSEQ * DH;
    const float* Vb = V + (size_t)b * LSEQ * DH;
    float*       Ob = O + (size_t)b * LSEQ * DH;

    // scores/8 in log2 domain: fold 0.125*log2(e) into Q cast
    const float QS = 0.125f * 1.44269504088896340736f;

    // ---- Q fragments (B-operand: col=q=lane&31, k = 8H+j within 16-chunk kb) ----
    bf16x8 qf[4];
#pragma unroll
    for (int kb = 0; kb < 4; ++kb) {
        const float* src = Qb + (size_t)(q0 + l31) * DH + 16 * kb + 8 * H;
        f4 a = *(const f4*)src;
        f4 c = *(const f4*)(src + 4);
        bf16x8 f;
        f[0] = f2bf(a[0] * QS); f[1] = f2bf(a[1] * QS);
        f[2] = f2bf(a[2] * QS); f[3] = f2bf(a[3] * QS);
        f[4] = f2bf(c[0] * QS); f[5] = f2bf(c[1] * QS);
        f[6] = f2bf(c[2] * QS); f[7] = f2bf(c[3] * QS);
        qf[kb] = f;
    }

    // staging registers (tile t+1 in flight)
    f4    kreg[4];
    float vreg[16];

    const int k_kv0 = (tid >> 3);        // +32*p
    const int k_d0  = (tid & 7) * 8;
    const int v_d   = tid & 63;
    const int v_g0  = tid >> 6;          // +4*hB

#define LOADK(KV0)                                                              \
    {                                                                           \
        _Pragma("unroll")                                                       \
        for (int p = 0; p < 2; ++p) {                                           \
            const float* src = Kb + (size_t)((KV0) + k_kv0 + 32 * p) * DH + k_d0; \
            kreg[2 * p]     = *(const f4*)src;                                  \
            kreg[2 * p + 1] = *(const f4*)(src + 4);                            \
        }                                                                       \
        _Pragma("unroll")                                                       \
        for (int hB = 0; hB < 2; ++hB) {                                        \
            _Pragma("unroll")                                                   \
            for (int j = 0; j < 8; ++j)                                         \
                vreg[8 * hB + j] =                                              \
                    Vb[(size_t)((KV0) + 8 * (v_g0 + 4 * hB) + j) * DH + v_d];   \
        }                                                                       \
    }

#define WRITEK(BUF)                                                             \
    {                                                                           \
        _Pragma("unroll")                                                       \
        for (int p = 0; p < 2; ++p) {                                           \
            const int kv = k_kv0 + 32 * p;                                      \
            union { bf16x8 v; uint32_t u[4]; } t;                               \
            t.u[0] = cvtpk(kreg[2 * p][0], kreg[2 * p][1]);                     \
            t.u[1] = cvtpk(kreg[2 * p][2], kreg[2 * p][3]);                     \
            t.u[2] = cvtpk(kreg[2 * p + 1][0], kreg[2 * p + 1][1]);             \
            t.u[3] = cvtpk(kreg[2 * p + 1][2], kreg[2 * p + 1][3]);             \
            *(bf16x8*)&k_lds[BUF][kv * DH + (k_d0 ^ ((kv & 7) << 3))] = t.v;    \
        }                                                                       \
        _Pragma("unroll")                                                       \
        for (int hB = 0; hB < 2; ++hB) {                                        \
            const int g = v_g0 + 4 * hB;                                        \
            union { bf16x8 v; uint32_t u[4]; } t;                               \
            t.u[0] = cvtpk(vreg[8 * hB + 0], vreg[8 * hB + 1]);                 \
            t.u[1] = cvtpk(vreg[8 * hB + 2], vreg[8 * hB + 3]);                 \
            t.u[2] = cvtpk(vreg[8 * hB + 4], vreg[8 * hB + 5]);                 \
            t.u[3] = cvtpk(vreg[8 * hB + 6], vreg[8 * hB + 7]);                 \
            *(bf16x8*)&v_lds[BUF][v_d * KVB + 8 * (g ^ (v_d & 7))] = t.v;       \
        }                                                                       \
    }

    // O^T accumulators
    f32x16 oacc0, oacc1;
#pragma unroll
    for (int i = 0; i < 16; ++i) { oacc0[i] = 0.f; oacc1[i] = 0.f; }

    float m_run = -INFINITY;
    float l_run = 0.f;

    // prologue: stage tile 0
    LOADK(0);
    WRITEK(0);
    __syncthreads();

    for (int it = 0; it < NT; ++it) {
        const int cur = it & 1;

        // issue next tile's global loads (latency hides under compute)
        if (it + 1 < NT) LOADK((it + 1) * KVB);

        // ---- S^T = K Q^T : lane holds S^T[kv=32c+(r&3)+8(r>>2)+4H][q=l31] ----
        f32x16 s0, s1;
#pragma unroll
        for (int i = 0; i < 16; ++i) { s0[i] = 0.f; s1[i] = 0.f; }
#pragma unroll
        for (int kb = 0; kb < 4; ++kb) {
            const int d0 = 16 * kb + 8 * H;
            bf16x8 kf0 = *(const bf16x8*)&k_lds[cur][(l31)      * DH + (d0 ^ ((l31 & 7) << 3))];
            bf16x8 kf1 = *(const bf16x8*)&k_lds[cur][(32 + l31) * DH + (d0 ^ ((l31 & 7) << 3))];
            s0 = __builtin_amdgcn_mfma_f32_32x32x16_bf16(kf0, qf[kb], s0, 0, 0, 0);
            s1 = __builtin_amdgcn_mfma_f32_32x32x16_bf16(kf1, qf[kb], s1, 0, 0, 0);
        }

        // ---- online softmax, per-lane (one q per lane), defer-max THR=8 ----
        float mx = fmaxf(s0[0], s0[1]);
#pragma unroll
        for (int i = 2; i < 16; ++i) mx = fmaxf(mx, s0[i]);
#pragma unroll
        for (int i = 0; i < 16; ++i) mx = fmaxf(mx, s1[i]);
        mx = fmaxf(mx, __shfl_xor(mx, 32));

        if (!__all(mx - m_run <= 8.0f)) {
            const float mn   = fmaxf(m_run, mx);
            const float corr = __builtin_amdgcn_exp2f(m_run - mn);
            m_run = mn;
            l_run *= corr;
#pragma unroll
            for (int i = 0; i < 16; ++i) { oacc0[i] *= corr; oacc1[i] *= corr; }
        }

        float rs = 0.f;
#pragma unroll
        for (int i = 0; i < 16; ++i) { s0[i] = __builtin_amdgcn_exp2f(s0[i] - m_run); rs += s0[i]; }
#pragma unroll
        for (int i = 0; i < 16; ++i) { s1[i] = __builtin_amdgcn_exp2f(s1[i] - m_run); rs += s1[i]; }
        rs += __shfl_xor(rs, 32);
        l_run += rs;

        // ---- P^T -> PV B-fragments via cvt_pk + permlane32_swap ----
        bf16x8 pa[4];
#define MAKE_PA(P, ks2, dst)                                                    \
        {                                                                       \
            uint32_t a1 = cvtpk(P[8*(ks2)+0], P[8*(ks2)+1]);                    \
            uint32_t b1 = cvtpk(P[8*(ks2)+4], P[8*(ks2)+5]);                    \
            uint32_t a2 = cvtpk(P[8*(ks2)+2], P[8*(ks2)+3]);                    \
            uint32_t b2 = cvtpk(P[8*(ks2)+6], P[8*(ks2)+7]);                    \
            asm volatile("v_permlane32_swap_b32 %0, %1" : "+v"(a1), "+v"(b1));  \
            asm volatile("v_permlane32_swap_b32 %0, %1" : "+v"(a2), "+v"(b2));  \
            union { bf16x8 v; uint32_t u[4]; } t;                               \
            t.u[0] = a1; t.u[1] = a2; t.u[2] = b1; t.u[3] = b2;                 \
            dst = t.v;                                                          \
        }
        MAKE_PA(s0, 0, pa[0]);
        MAKE_PA(s0, 1, pa[1]);
        MAKE_PA(s1, 0, pa[2]);
        MAKE_PA(s1, 1, pa[3]);
#undef MAKE_PA

        // ---- O^T += V^T P^T ----
#pragma unroll
        for (int ks = 0; ks < 4; ++ks) {
            const int d0g = 2 * ks + H;
            bf16x8 vf0 = *(const bf16x8*)&v_lds[cur][(l31)      * KVB + 8 * (d0g ^ (l31 & 7))];
            bf16x8 vf1 = *(const bf16x8*)&v_lds[cur][(32 + l31) * KVB + 8 * (d0g ^ (l31 & 7))];
            oacc0 = __builtin_amdgcn_mfma_f32_32x32x16_bf16(vf0, pa[ks], oacc0, 0, 0, 0);
            oacc1 = __builtin_amdgcn_mfma_f32_32x32x16_bf16(vf1, pa[ks], oacc1, 0, 0, 0);
        }

        // ---- write next tile into the other buffer (waits vmcnt here) ----
        if (it + 1 < NT) WRITEK(cur ^ 1);
        __syncthreads();
    }

    // ---- epilogue: O[q][d] = O^T/l ----
    const float inv = 1.0f / l_run;
    const int q = q0 + l31;
#pragma unroll
    for (int k = 0; k < 4; ++k) {
        f4 o0, o1;
#pragma unroll
        for (int m = 0; m < 4; ++m) { o0[m] = oacc0[4*k+m] * inv; o1[m] = oacc1[4*k+m] * inv; }
        *(f4*)&Ob[(size_t)q * DH +      8 * k + 4 * H] = o0;
        *(f4*)&Ob[(size_t)q * DH + 32 + 8 * k + 4 * H] = o1;
    }
#undef LOADK
#undef WRITEK
}

extern "C" void kernel_launch(void* const* d_in, const int* in_sizes, int n_in,
                              void* d_out, int out_size, void* d_ws, size_t ws_size,
                              hipStream_t stream) {
    (void)in_sizes; (void)n_in; (void)d_ws; (void)ws_size; (void)out_size;
    const float* q = (const float*)d_in[0];
    const float* k = (const float*)d_in[1];
    const float* v = (const float*)d_in[2];
    float* o = (float*)d_out;
    dim3 grid(NB * (LSEQ / QB));
    dim3 block(256);
    hipLaunchKernelGGL(fa_fwd, grid, block, 0, stream, q, k, v, o);
}